// Round 13
// baseline (238.949 us; speedup 1.0000x reference)
//
#include <hip/hip_runtime.h>
#include <stdint.h>

// DecayModel: out[b,i,h] = (fwd[i] + bwd[i]) / norm[i], decay = 0.5
//   fwd[i] = sum_{k<=i} 0.5^{i-k} x[k],  bwd[i] = sum_{k>=i} 0.5^{k-i} x[k]
//   norm[i] = 4 - 2^{-i} - 2^{-(S-1-i)}   (== 4.0f exactly for interior i)
//
// R18 -> R19: single-variable A/B -- nontemporal stores OUT, plain stores IN.
// R17/R18 falsified both residual theories: the DMA pipeline ran as designed
// (VGPR=88, correct vmcnt ledger, contiguous per-wave 4KB row streams) and
// still hit 88us / 2.45 TB/s. Little's law: ~64KB DMA reads in flight per
// CU yet 5.5us per 64KB iteration -> ~16MB outstanding device-wide at only
// ~3 TB/s = a memory-SYSTEM throughput ceiling for this traffic mix, not a
// concurrency limit. The one variable present in EVERY round since R5:
// __builtin_nontemporal_store. NT bypasses L2/L3 allocation and streams 1KB
// scattered bursts from 512 concurrent streams straight at the memory
// controllers interleaved with reads (worst case for DRAM bus-turnaround /
// row-buffer scheduling), and forces all 131MB to HBM synchronously inside
// the kernel. Plain stores allocate in L2/L3; TCC writes back lazily in
// large well-scheduled batches. Everything else byte-identical to R17.
// Predict: if write-path theory right, dur 88 -> 55-65us, composite BW
// 2.45 -> 3.3-4 TB/s (WRITE_SIZE may undercount into post-kernel lazy
// writeback). If flat ~88us: NT exonerated; next = v4f x 16-waves corner.

constexpr int B = 16;
constexpr int S = 2048;
constexpr int HV = 256;          // v4f per row (1024 floats)
constexpr int C = 64;            // chunk rows per block
constexpr int W = 4;             // subtile rows (== waves per block)
constexpr int NT = C / W;        // 16 iterations
constexpr int THREADS = 256;
constexpr int NCHUNK = S / C;    // 32
constexpr int NBLK = B * NCHUNK; // 512 blocks -> 2 per CU
constexpr int NXCD = 8;

typedef float v4f __attribute__((ext_vector_type(4)));

__device__ __forceinline__ void gload16(const v4f* g, v4f* l) {
    // HBM -> LDS direct, 16B/lane; LDS dest = wave-uniform base + lane*16.
    __builtin_amdgcn_global_load_lds(
        (const __attribute__((address_space(1))) uint32_t*)g,
        (__attribute__((address_space(3))) uint32_t*)l, 16, 0, 0);
}

// Stage one 4-row subtile: wave w DMAs global row (row0+w, clamped) into
// LDS row w of buf -- 4 x 1KB instructions, contiguous 4KB per wave.
__device__ __forceinline__ void stage(const v4f* xb, int row0,
                                      v4f (*buf)[HV], int w, int lane) {
    int g = row0 + w;
    g = g < 0 ? 0 : (g > S - 1 ? S - 1 : g);
    const v4f* src = xb + (size_t)g * HV + lane;
#pragma unroll
    for (int j = 0; j < 4; ++j) gload16(src + j * 64, &buf[w][j * 64]);
}

__global__ __launch_bounds__(THREADS, 2) void decay_kernel(
    const v4f* __restrict__ x, v4f* __restrict__ out) {
    __shared__ v4f lds[4][W][HV];  // 4 bufs x 4 rows x 4KB = 64 KiB

    // Bijective XCD swizzle (512 % 8 == 0): each XCD gets 64 consecutive
    // work items = 2 whole batches; chunk-neighbors share halo rows in L2.
    const int bid = blockIdx.x;
    const int swz = (bid & (NXCD - 1)) * (NBLK / NXCD) + (bid >> 3);
    const int cc = swz & (NCHUNK - 1);
    const int b = swz / NCHUNK;
    const int s0 = cc * C;
    const bool edge = (cc == 0) | (cc == NCHUNK - 1);

    const int tid = threadIdx.x;
    const int w = tid >> 6;
    const int lane = tid & 63;
    const v4f* __restrict__ xb = x + (size_t)b * S * HV;
    v4f* __restrict__ ob = out + (size_t)b * S * HV + tid;

    // ---- prologue: halo subs -2,-1 -> bufs 2,3; subs 0,1 -> bufs 0,1 ----
    stage(xb, s0 - 8, lds[2], w, lane);
    stage(xb, s0 - 4, lds[3], w, lane);
    stage(xb, s0, lds[0], w, lane);
    stage(xb, s0 + 4, lds[1], w, lane);
    asm volatile("s_waitcnt vmcnt(8)" ::: "memory");  // halo done; 0,1 fly
    __builtin_amdgcn_s_barrier();

    // fwd carry-in: 8-tap truncated scan over the halo (zero for chunk 0)
    v4f facc = (v4f)0.0f;
    if (cc > 0) {
#pragma unroll
        for (int r = 0; r < W; ++r) facc = 0.5f * facc + lds[2][r][tid];
#pragma unroll
        for (int r = 0; r < W; ++r) facc = 0.5f * facc + lds[3][r][tid];
    }
    // pin the halo reads + carry chain before buf2 is overwritten
    asm volatile("s_waitcnt lgkmcnt(0)" ::: "memory");
    __builtin_amdgcn_sched_barrier(0);
    __builtin_amdgcn_s_barrier();
    stage(xb, s0 + 8, lds[2], w, lane);  // sub 2 (halo consumed)

    // ---- main loop: NT subtiles ----
    for (int m = 0; m < NT; ++m) {
        // drain loads(m-1) (which filled buf (m+2)); keep stores in flight.
        if (m == 0)
            asm volatile("s_waitcnt vmcnt(0)" ::: "memory");  // prologue only
        else
            asm volatile("s_waitcnt vmcnt(4)" ::: "memory");
        __builtin_amdgcn_s_barrier();

        // prefetch subtile m+3 (subs NT, NT+1 = right halo; clamped rows)
        if (m + 3 <= NT + 1)
            stage(xb, s0 + (m + 3) * W, lds[(m + 3) & 3], w, lane);

        // ---- forward recurrence over subtile m (exact within chunk) ----
        const v4f fprev = facc;
        v4f f[W];
#pragma unroll
        for (int r = 0; r < W; ++r) {
            facc = 0.5f * facc + lds[m & 3][r][tid];
            f[r] = facc;
        }

        // ---- backward 8-tap lookahead from subs m+1, m+2 ----
        v4f bacc = (v4f)0.0f;
        const int la0 = s0 + (m + 1) * W;
#pragma unroll
        for (int j = 2 * W - 1; j >= 0; --j) {
            v4f t = (j < W) ? lds[(m + 1) & 3][j][tid]
                            : lds[(m + 2) & 3][j - W][tid];
            if (la0 + j >= S) t = (v4f)0.0f;  // rows past end contribute 0
            bacc = 0.5f * bacc + t;
        }

        // ---- backward march + combine + store (PLAIN stores: let L2/L3
        //      absorb the write stream; TCC writes back in big batches) ----
#pragma unroll
        for (int r = W - 1; r >= 0; --r) {
            const v4f fr = f[r];
            const v4f fm_ = r ? f[r - 1] : fprev;
            bacc = 0.5f * bacc + (fr - 0.5f * fm_);  // recover x, extend bwd
            const int i = s0 + m * W + r;
            float rn = 0.25f;  // norm == 4.0f exactly for interior rows
            if (edge)
                rn = 1.0f / (4.0f - exp2f((float)(-i)) -
                             exp2f((float)(i - (S - 1))));
            ob[(size_t)i * HV] = (fr + bacc) * rn;
        }
    }
}

extern "C" void kernel_launch(void* const* d_in, const int* in_sizes, int n_in,
                              void* d_out, int out_size, void* d_ws,
                              size_t ws_size, hipStream_t stream) {
    const v4f* x = (const v4f*)d_in[0];
    v4f* out = (v4f*)d_out;
    decay_kernel<<<dim3(NBLK), THREADS, 0, stream>>>(x, out);
}